// Round 4
// baseline (972.686 us; speedup 1.0000x reference)
//
#include <hip/hip_runtime.h>

// ensembleThreeModel: 3-way majority-vote ensemble over softmax outputs.
// B = 65536 rows, C = 1000 classes, fp32.
// One block (256 threads) per row; 250 threads each own one float4 slice of
// the row from each of the 3 models. Single pass: registers hold the data
// across the argmax reduction, so HBM traffic is the 1.31 GB floor.

#define NUM_C   1000
#define NUM_C4  250   // float4 chunks per row

// Pack (value, index) so that u64 max == argmax with lowest-index tie-break.
// Softmax outputs are >= 0, so the raw float bit pattern is monotone in value.
__device__ __forceinline__ unsigned long long pk(float v, int idx) {
    return ((unsigned long long)__float_as_uint(v) << 32) | (unsigned int)(~idx);
}
__device__ __forceinline__ unsigned long long pmax(unsigned long long a,
                                                   unsigned long long b) {
    return a > b ? a : b;
}

__global__ __launch_bounds__(256) void ensemble3_kernel(
    const float* __restrict__ o1, const float* __restrict__ o2,
    const float* __restrict__ o3,
    float* __restrict__ acp,          // avg_correct_prob [B,C]
    float* __restrict__ avg,          // avg_prob         [B,C]
    float* __restrict__ pred_f,       // preds as f32 (layout A) or null
    long long* __restrict__ pred_i)   // preds as i64 (layout B) or null
{
    const int row = blockIdx.x;
    const int tid = threadIdx.x;
    const long long base = (long long)row * NUM_C;

    float4 v1 = make_float4(0.f, 0.f, 0.f, 0.f);
    float4 v2 = v1, v3 = v1;
    unsigned long long p1 = 0ull, p2 = 0ull, p3 = 0ull;
    const bool active = tid < NUM_C4;

    if (active) {
        const long long off = base + 4LL * tid;
        v1 = *(const float4*)(o1 + off);
        v2 = *(const float4*)(o2 + off);
        v3 = *(const float4*)(o3 + off);
        const int i0 = 4 * tid;
        p1 = pmax(pmax(pk(v1.x, i0),     pk(v1.y, i0 + 1)),
                  pmax(pk(v1.z, i0 + 2), pk(v1.w, i0 + 3)));
        p2 = pmax(pmax(pk(v2.x, i0),     pk(v2.y, i0 + 1)),
                  pmax(pk(v2.z, i0 + 2), pk(v2.w, i0 + 3)));
        p3 = pmax(pmax(pk(v3.x, i0),     pk(v3.y, i0 + 1)),
                  pmax(pk(v3.z, i0 + 2), pk(v3.w, i0 + 3)));
    }

    // Wave64 butterfly reduce (6 steps), then 4-wave LDS combine.
    #pragma unroll
    for (int off = 32; off > 0; off >>= 1) {
        p1 = pmax(p1, __shfl_xor(p1, off));
        p2 = pmax(p2, __shfl_xor(p2, off));
        p3 = pmax(p3, __shfl_xor(p3, off));
    }
    __shared__ unsigned long long red[3][4];
    const int wave = tid >> 6;
    if ((tid & 63) == 0) {
        red[0][wave] = p1; red[1][wave] = p2; red[2][wave] = p3;
    }
    __syncthreads();
    const unsigned long long q1 =
        pmax(pmax(red[0][0], red[0][1]), pmax(red[0][2], red[0][3]));
    const unsigned long long q2 =
        pmax(pmax(red[1][0], red[1][1]), pmax(red[1][2], red[1][3]));
    const unsigned long long q3 =
        pmax(pmax(red[2][0], red[2][1]), pmax(red[2][2], red[2][3]));
    const int pred1 = (int)(~(unsigned int)q1);
    const int pred2 = (int)(~(unsigned int)q2);
    const int pred3 = (int)(~(unsigned int)q3);

    // Majority vote, exactly mirroring the reference's where-chain.
    const bool eq12 = pred1 == pred2;
    const bool eq13 = pred1 == pred3;
    const bool eq23 = pred2 == pred3;
    const int cmax  = (eq12 && eq13) ? 3 : ((eq12 || eq13 || eq23) ? 2 : 1);
    const int maj   = (eq12 || eq13) ? pred1 : (eq23 ? pred2 : pred1);
    const int value = (cmax < 2) ? pred3 : maj;

    if (tid == 0) {
        if (pred_i) pred_i[row] = (long long)value;
        else        pred_f[row] = (float)value;
    }

    if (active) {
        const float m1 = (pred1 == value) ? 1.0f : 0.0f;
        const float m2 = (pred2 == value) ? 1.0f : 0.0f;
        const float m3 = (pred3 == value) ? 1.0f : 0.0f;
        const float denom = (float)cmax;

        float4 a, g;
        a.x = (v1.x * m1 + v2.x * m2 + v3.x * m3) / denom;
        a.y = (v1.y * m1 + v2.y * m2 + v3.y * m3) / denom;
        a.z = (v1.z * m1 + v2.z * m2 + v3.z * m3) / denom;
        a.w = (v1.w * m1 + v2.w * m2 + v3.w * m3) / denom;
        g.x = (v1.x + v2.x + v3.x) / 3.0f;
        g.y = (v1.y + v2.y + v3.y) / 3.0f;
        g.z = (v1.z + v2.z + v3.z) / 3.0f;
        g.w = (v1.w + v2.w + v3.w) / 3.0f;

        const long long off = base + 4LL * tid;
        *(float4*)(acp + off) = a;
        *(float4*)(avg + off) = g;
    }
}

extern "C" void kernel_launch(void* const* d_in, const int* in_sizes, int n_in,
                              void* d_out, int out_size, void* d_ws, size_t ws_size,
                              hipStream_t stream) {
    const float* o1 = (const float*)d_in[0];
    const float* o2 = (const float*)d_in[1];
    const float* o3 = (const float*)d_in[2];

    const long long BC = in_sizes[0];        // B * C
    const long long B  = BC / NUM_C;

    float* outf = (float*)d_out;
    float*     pred_f = nullptr;
    long long* pred_i = nullptr;
    float*     acp;
    float*     avg;

    if ((long long)out_size == 2LL * B + 2LL * BC) {
        // Layout B: preds kept as raw int64 (occupy 2*B float slots).
        pred_i = (long long*)d_out;
        acp = outf + 2LL * B;
    } else {
        // Layout A (default): preds converted to the common float dtype.
        pred_f = outf;
        acp = outf + B;
    }
    avg = acp + BC;

    ensemble3_kernel<<<dim3((unsigned)B), dim3(256), 0, stream>>>(
        o1, o2, o3, acp, avg, pred_f, pred_i);
}